// Round 5
// baseline (1149.141 us; speedup 1.0000x reference)
//
#include <hip/hip_runtime.h>
#include <hip/hip_bf16.h>

// N=12288, D=256.
//   e[i,j] = lrelu(u[i] + v[j]);  u = h_eu@a1 + h_lo@a3, v = h_po@a2
//   q = exp2(lrelu*log2e - SHIFT2) masked by adj>0 (constant shift; exp scale-free)
//   out_i = (0.5*deg_i/denom_i) * (q_i @ h_po) + 0.5 * (adj_i @ h_po)
//
// fused4: ZERO barriers, ZERO LDS. BM=16 stripe per block; 4 waves split D
// (dq owns 4 of 16 dt tiles). Each wave lane-locally scores its A-fragments
// (x4 redundant across dq waves - buys full wave independence), loads B
// fragments straight from bf16 h_poT, keeps 32 acc VGPRs, reduces denom/deg
// via shfl only. Grid 768 = exactly 3 blocks/CU. Reg pipeline: adj depth-3,
// B/v depth-2 (x6 unrolled loop -> static reg indices).

#define NN 12288
#define DD 256
#define STEPS (NN / 32)       // 384
#define LOG2E 1.44269504f
#define SHIFT2 36.067376f     // 25*log2e

typedef __attribute__((ext_vector_type(8))) short s16x8;
typedef __attribute__((ext_vector_type(4))) float f32x4;

__device__ __forceinline__ unsigned short f2bf(float f) {
  unsigned u = __builtin_bit_cast(unsigned, f);
  u += 0x7FFFu + ((u >> 16) & 1u);
  return (unsigned short)(u >> 16);
}
__device__ __forceinline__ unsigned pack_bf2(float a, float b) {
  unsigned short lo = __builtin_bit_cast(unsigned short, __float2bfloat16(a));
  unsigned short hi = __builtin_bit_cast(unsigned short, __float2bfloat16(b));
  return (unsigned)lo | ((unsigned)hi << 16);
}
__device__ __forceinline__ float exp2_hw(float x) {
  float r;
  asm("v_exp_f32 %0, %1" : "=v"(r) : "v"(x));
  return r;
}

// ---------------- prep: u2, v2 (pre-scaled by log2e) ----------------
__global__ __launch_bounds__(256) void prep_uv(
    const float* __restrict__ h_eu, const float* __restrict__ h_po,
    const float* __restrict__ h_lo, const float* __restrict__ a1,
    const float* __restrict__ a2, const float* __restrict__ a3,
    float* __restrict__ u, float* __restrict__ v) {
  const int t = threadIdx.x;
  const int wave = t >> 6, lane = t & 63;
  const int r0 = blockIdx.x * 64;
  for (int rr = 0; rr < 16; ++rr) {
    const int row = r0 + wave * 16 + rr;
    const float* pe = h_eu + (size_t)row * DD;
    const float* pl = h_lo + (size_t)row * DD;
    const float* pp = h_po + (size_t)row * DD;
    float su = 0.f, sv = 0.f;
#pragma unroll
    for (int c = 0; c < 4; ++c) {
      const int d = lane + c * 64;
      su = fmaf(pe[d], a1[d], su);
      su = fmaf(pl[d], a3[d], su);
      sv = fmaf(pp[d], a2[d], sv);
    }
#pragma unroll
    for (int m = 32; m; m >>= 1) {
      su += __shfl_xor(su, m, 64);
      sv += __shfl_xor(sv, m, 64);
    }
    if (lane == 0) { u[row] = su * LOG2E; v[row] = sv * LOG2E; }
  }
}

// ---------------- prep: h_poT (bf16, [D][N]) ----------------
__global__ __launch_bounds__(256) void prep_T(
    const float* __restrict__ hpo, unsigned short* __restrict__ h_poT) {
  const int t = threadIdx.x;
  const int r0 = blockIdx.x * 64;
  unsigned short* dst = h_poT + (size_t)t * NN + r0;
#pragma unroll
  for (int c = 0; c < 16; ++c) {
    unsigned short x0 = f2bf(hpo[(size_t)(r0 + c * 4 + 0) * DD + t]);
    unsigned short x1 = f2bf(hpo[(size_t)(r0 + c * 4 + 1) * DD + t]);
    unsigned short x2 = f2bf(hpo[(size_t)(r0 + c * 4 + 2) * DD + t]);
    unsigned short x3 = f2bf(hpo[(size_t)(r0 + c * 4 + 3) * DD + t]);
    ((uint2*)dst)[c] = make_uint2((unsigned)x0 | ((unsigned)x1 << 16),
                                  (unsigned)x2 | ((unsigned)x3 << 16));
  }
}

// ---------------- fused4: barrier-free, LDS-free, wave-independent ----------
__global__ __launch_bounds__(256, 3) void fused4(
    const float* __restrict__ adj, const float* __restrict__ u2,
    const float* __restrict__ v2, const unsigned short* __restrict__ h_poT,
    float* __restrict__ out) {
  const int t = threadIdx.x;
  const int dq = t >> 6;              // wave id: owns dt = dq*4 .. dq*4+3
  const int lane = t & 63;
  const int lrow = lane & 15;         // A row / B col within fragment
  const int kgrp = lane >> 4;         // k-slice: k = kgrp*8 .. +8 (mod 32)
  const int i0 = blockIdx.x * 16;
  const int row = i0 + lrow;

  const float u_r = u2[row];

  const float* aptr = adj + (size_t)row * NN + kgrp * 8;
  const float* vptr = v2 + kgrp * 8;
  const unsigned short* bptr0 = h_poT + (size_t)(dq * 64 + 0 * 16 + lrow) * NN + kgrp * 8;
  const unsigned short* bptr1 = h_poT + (size_t)(dq * 64 + 1 * 16 + lrow) * NN + kgrp * 8;
  const unsigned short* bptr2 = h_poT + (size_t)(dq * 64 + 2 * 16 + lrow) * NN + kgrp * 8;
  const unsigned short* bptr3 = h_poT + (size_t)(dq * 64 + 3 * 16 + lrow) * NN + kgrp * 8;

  f32x4 acc1[4] = {};  // q   @ B  (4 dt tiles)
  f32x4 acc2[4] = {};  // adj @ B
  float qsum = 0.f, asum = 0.f;

  // register pipeline: adj depth-3, B & v depth-2
  float4 A[3][2];
  uint4  B[2][4];
  float4 V[2][2];

  auto loadA = [&](int slot, int jt) {
    const int j = (jt >= STEPS ? 0 : jt) * 32;
    A[slot][0] = *(const float4*)(aptr + j);
    A[slot][1] = *(const float4*)(aptr + j + 4);
  };
  auto loadB = [&](int slot, int jt) {
    const int j = (jt >= STEPS ? 0 : jt) * 32;
    B[slot][0] = *(const uint4*)(bptr0 + j);
    B[slot][1] = *(const uint4*)(bptr1 + j);
    B[slot][2] = *(const uint4*)(bptr2 + j);
    B[slot][3] = *(const uint4*)(bptr3 + j);
  };
  auto loadV = [&](int slot, int jt) {
    const int j = (jt >= STEPS ? 0 : jt) * 32;
    V[slot][0] = *(const float4*)(vptr + j);
    V[slot][1] = *(const float4*)(vptr + j + 4);
  };

  loadA(0, 0); loadA(1, 1); loadA(2, 2);
  loadB(0, 0); loadB(1, 1);
  loadV(0, 0); loadV(1, 1);

  for (int jt = 0; jt < STEPS; jt += 6) {
#pragma unroll
    for (int s = 0; s < 6; ++s) {
      const int j = jt + s;
      const int sa = s % 3, sb = s & 1;

      // score this lane's 8 elements (A-fragment row lrow, k kgrp*8..+8)
      const float cf[8] = {A[sa][0].x, A[sa][0].y, A[sa][0].z, A[sa][0].w,
                           A[sa][1].x, A[sa][1].y, A[sa][1].z, A[sa][1].w};
      const float vf[8] = {V[sb][0].x, V[sb][0].y, V[sb][0].z, V[sb][0].w,
                           V[sb][1].x, V[sb][1].y, V[sb][1].z, V[sb][1].w};
      unsigned qp[4], app[4];
#pragma unroll
      for (int e = 0; e < 8; e += 2) {
        const float t0 = u_r + vf[e], t1 = u_r + vf[e + 1];
        const float x0 = fmaxf(t0, 0.01f * t0), x1 = fmaxf(t1, 0.01f * t1);
        float q0 = exp2_hw(x0 - SHIFT2), q1 = exp2_hw(x1 - SHIFT2);
        q0 = (cf[e] > 0.f) ? q0 : 0.f;
        q1 = (cf[e + 1] > 0.f) ? q1 : 0.f;
        qsum += q0; qsum += q1;
        asum += cf[e]; asum += cf[e + 1];
        qp[e >> 1]  = pack_bf2(q0, q1);
        app[e >> 1] = pack_bf2(cf[e], cf[e + 1]);
      }
      const s16x8 qa = __builtin_bit_cast(s16x8, *(uint4*)qp);
      const s16x8 aa = __builtin_bit_cast(s16x8, *(uint4*)app);

#pragma unroll
      for (int di = 0; di < 4; ++di) {
        const s16x8 bb = __builtin_bit_cast(s16x8, B[sb][di]);
        acc1[di] = __builtin_amdgcn_mfma_f32_16x16x32_bf16(qa, bb, acc1[di], 0, 0, 0);
        acc2[di] = __builtin_amdgcn_mfma_f32_16x16x32_bf16(aa, bb, acc2[di], 0, 0, 0);
      }

      // refill the slots just consumed
      loadA(sa, j + 3);
      loadB(sb, j + 2);
      loadV(sb, j + 2);
    }
  }

  // denom/deg: every wave holds full row sums -> shfl-only reduce over kgrp
  qsum += __shfl_xor(qsum, 16, 64); qsum += __shfl_xor(qsum, 32, 64);
  asum += __shfl_xor(asum, 16, 64); asum += __shfl_xor(asum, 32, 64);
  const float coef_lane = qsum > 0.f ? 0.5f * asum / qsum : 0.f;  // for row lrow

  // epilogue: out[i0+r][dq*64+di*16+lrow] = coef_r*acc1 + 0.5*acc2
#pragma unroll
  for (int di = 0; di < 4; ++di) {
    const int col = dq * 64 + di * 16 + lrow;
#pragma unroll
    for (int g = 0; g < 4; ++g) {
      const int r = kgrp * 4 + g;
      const float cr = __shfl(coef_lane, r, 16);  // lane holding row r's coef
      out[(size_t)(i0 + r) * DD + col] = cr * acc1[di][g] + 0.5f * acc2[di][g];
    }
  }
}

// ---------------- fallback (small ws): round-2 proven kernel ----------------
__global__ __launch_bounds__(256) void fused_fb(
    const float* __restrict__ adj, const float* __restrict__ u,
    const float* __restrict__ v, const float* __restrict__ hpo,
    float* __restrict__ out) {
#define BMF 32
#define LDA 40
  __shared__ unsigned short qlds[BMF][LDA];
  __shared__ unsigned short alds[BMF][LDA];
  __shared__ unsigned short btf[DD][LDA];
  __shared__ float denom_s[BMF], deg_s[BMF], coef_s[BMF];

  const int t = threadIdx.x;
  const int wave = t >> 6, lane = t & 63;
  const int i0 = blockIdx.x * BMF;
  const int sr = t >> 3;
  const int sc = (t & 7) * 4;
  const float u_r = u[i0 + sr];
  const int d0 = wave * 64;
  const int lrow = lane & 15;
  const int kgrp = lane >> 4;

  f32x4 acc1[2][4] = {};
  f32x4 acc2[2][4] = {};
  float qsum = 0.f, asum = 0.f;

  const float* arow = adj + (size_t)(i0 + sr) * NN + sc;
  float4 a_cur = *(const float4*)(arow);

  constexpr int NSTEP = NN / 32;
  for (int jt = 0; jt < NSTEP; ++jt) {
    const int j = jt * 32;
    float4 a_nxt;
    const bool has_next = (jt + 1 < NSTEP);
    if (has_next) a_nxt = *(const float4*)(arow + j + 32);
    const float4 vv = *(const float4*)(v + j + sc);
    unsigned short qb[4], ab[4];
    {
      const float aa4[4] = {a_cur.x, a_cur.y, a_cur.z, a_cur.w};
      const float vvv[4] = {vv.x, vv.y, vv.z, vv.w};
#pragma unroll
      for (int k = 0; k < 4; ++k) {
        const float a = aa4[k];
        const float s = u_r + vvv[k];
        const float x = fmaxf(s, 0.01f * s);
        const float q = (a > 0.f) ? exp2_hw(x - SHIFT2) : 0.f;
        qsum += q;
        asum += a;
        qb[k] = f2bf(q);
        ab[k] = f2bf(a);
      }
    }
    *(uint2*)&qlds[sr][sc] = make_uint2((unsigned)qb[0] | ((unsigned)qb[1] << 16),
                                        (unsigned)qb[2] | ((unsigned)qb[3] << 16));
    *(uint2*)&alds[sr][sc] = make_uint2((unsigned)ab[0] | ((unsigned)ab[1] << 16),
                                        (unsigned)ab[2] | ((unsigned)ab[3] << 16));
    {
      const int br = t >> 3;
      const float* src = hpo + (size_t)(j + br) * DD;
#pragma unroll
      for (int cc = 0; cc < 8; ++cc) {
        const int c = (t & 7) * 4 + cc * 32;
        const float4 hv = *(const float4*)(src + c);
        btf[c + 0][br] = f2bf(hv.x);
        btf[c + 1][br] = f2bf(hv.y);
        btf[c + 2][br] = f2bf(hv.z);
        btf[c + 3][br] = f2bf(hv.w);
      }
    }
    __syncthreads();

    const s16x8 qa0 = *(const s16x8*)&qlds[lrow][kgrp * 8];
    const s16x8 qa1 = *(const s16x8*)&qlds[16 + lrow][kgrp * 8];
    const s16x8 ad0 = *(const s16x8*)&alds[lrow][kgrp * 8];
    const s16x8 ad1 = *(const s16x8*)&alds[16 + lrow][kgrp * 8];
#pragma unroll
    for (int dt = 0; dt < 4; ++dt) {
      const s16x8 b = *(const s16x8*)&btf[d0 + dt * 16 + lrow][kgrp * 8];
      acc1[0][dt] = __builtin_amdgcn_mfma_f32_16x16x32_bf16(qa0, b, acc1[0][dt], 0, 0, 0);
      acc1[1][dt] = __builtin_amdgcn_mfma_f32_16x16x32_bf16(qa1, b, acc1[1][dt], 0, 0, 0);
      acc2[0][dt] = __builtin_amdgcn_mfma_f32_16x16x32_bf16(ad0, b, acc2[0][dt], 0, 0, 0);
      acc2[1][dt] = __builtin_amdgcn_mfma_f32_16x16x32_bf16(ad1, b, acc2[1][dt], 0, 0, 0);
    }
    __syncthreads();
    if (has_next) a_cur = a_nxt;
  }
#pragma unroll
  for (int m = 1; m <= 4; m <<= 1) {
    qsum += __shfl_xor(qsum, m, 64);
    asum += __shfl_xor(asum, m, 64);
  }
  if ((t & 7) == 0) { denom_s[sr] = qsum; deg_s[sr] = asum; }
  __syncthreads();
  if (t < BMF) {
    const float dn = denom_s[t];
    coef_s[t] = dn > 0.f ? 0.5f * deg_s[t] / dn : 0.f;
  }
  __syncthreads();
#pragma unroll
  for (int f = 0; f < 2; ++f) {
#pragma unroll
    for (int dt = 0; dt < 4; ++dt) {
      const int col = d0 + dt * 16 + lrow;
#pragma unroll
      for (int g = 0; g < 4; ++g) {
        const int r = f * 16 + kgrp * 4 + g;
        out[(size_t)(i0 + r) * DD + col] =
            coef_s[r] * acc1[f][dt][g] + 0.5f * acc2[f][dt][g];
      }
    }
  }
}

extern "C" void kernel_launch(void* const* d_in, const int* in_sizes, int n_in,
                              void* d_out, int out_size, void* d_ws, size_t ws_size,
                              hipStream_t stream) {
  const float* h_eu = (const float*)d_in[0];
  const float* h_po = (const float*)d_in[1];
  const float* h_lo = (const float*)d_in[2];
  const float* adj  = (const float*)d_in[3];
  const float* a1   = (const float*)d_in[4];
  const float* a2   = (const float*)d_in[5];
  const float* a3   = (const float*)d_in[6];
  float* out = (float*)d_out;

  const size_t need_uv   = (size_t)2 * NN * 4;
  const size_t need_full = need_uv + (size_t)NN * DD * 2;  // 6,389,760 B
  float* u = (float*)d_ws;
  float* v = u + NN;
  unsigned short* h_poT = (unsigned short*)(v + NN);
  const bool big_ws = ws_size >= need_full;

  prep_uv<<<NN / 64, 256, 0, stream>>>(h_eu, h_po, h_lo, a1, a2, a3, u, v);
  if (big_ws) {
    prep_T<<<NN / 64, 256, 0, stream>>>(h_po, h_poT);
    fused4<<<NN / 16, 256, 0, stream>>>(adj, u, v, h_poT, out);
  } else {
    fused_fb<<<NN / 32, 256, 0, stream>>>(adj, u, v, h_po, out);
  }
}

// Round 6
// 727.060 us; speedup vs baseline: 1.5805x; 1.5805x over previous
//
#include <hip/hip_runtime.h>
#include <hip/hip_bf16.h>

// N=12288, D=256. Two-pass:
//   pass 1 (stats): coef_i = 0.5*deg_i/denom_i   (streaming reduce over adj)
//   pass 2 (gemm):  out = A @ h_po,  A_ij = coef_i*q_ij + 0.5*adj_ij  (ONE matrix)
//   q_ij = exp2(lrelu(u_i+v_j) - SHIFT2) masked by adj>0; u,v pre-scaled by log2e.
// pass 2: adj via global_load_lds (pre-swizzled source, XOR-swizzled ds_read),
// K-chunk 128 double-buffered, B burst-loaded from L2-resident bf16 h_poT.

#define NN 12288
#define DD 256
#define KC 128
#define NCH (NN / KC)         // 96
#define LOG2E 1.44269504f
#define SHIFT2 36.067376f     // 25*log2e

typedef __attribute__((ext_vector_type(8))) short s16x8;
typedef __attribute__((ext_vector_type(4))) float f32x4;

__device__ __forceinline__ unsigned short f2bf(float f) {
  unsigned u = __builtin_bit_cast(unsigned, f);
  u += 0x7FFFu + ((u >> 16) & 1u);
  return (unsigned short)(u >> 16);
}
__device__ __forceinline__ unsigned pack_bf2(float a, float b) {
  unsigned short lo = __builtin_bit_cast(unsigned short, __float2bfloat16(a));
  unsigned short hi = __builtin_bit_cast(unsigned short, __float2bfloat16(b));
  return (unsigned)lo | ((unsigned)hi << 16);
}
__device__ __forceinline__ float exp2_hw(float x) {
  float r;
  asm("v_exp_f32 %0, %1" : "=v"(r) : "v"(x));
  return r;
}
__device__ __forceinline__ void gl_lds16(const float* g, float* l) {
  __builtin_amdgcn_global_load_lds(
      (const __attribute__((address_space(1))) void*)g,
      (__attribute__((address_space(3))) void*)l, 16, 0, 0);
}

// ---------------- prep: u2, v2 (pre-scaled by log2e) ----------------
__global__ __launch_bounds__(256) void prep_uv(
    const float* __restrict__ h_eu, const float* __restrict__ h_po,
    const float* __restrict__ h_lo, const float* __restrict__ a1,
    const float* __restrict__ a2, const float* __restrict__ a3,
    float* __restrict__ u, float* __restrict__ v) {
  const int t = threadIdx.x;
  const int wave = t >> 6, lane = t & 63;
  const int r0 = blockIdx.x * 64;
  for (int rr = 0; rr < 16; ++rr) {
    const int row = r0 + wave * 16 + rr;
    const float* pe = h_eu + (size_t)row * DD;
    const float* pl = h_lo + (size_t)row * DD;
    const float* pp = h_po + (size_t)row * DD;
    float su = 0.f, sv = 0.f;
#pragma unroll
    for (int c = 0; c < 4; ++c) {
      const int d = lane + c * 64;
      su = fmaf(pe[d], a1[d], su);
      su = fmaf(pl[d], a3[d], su);
      sv = fmaf(pp[d], a2[d], sv);
    }
#pragma unroll
    for (int m = 32; m; m >>= 1) {
      su += __shfl_xor(su, m, 64);
      sv += __shfl_xor(sv, m, 64);
    }
    if (lane == 0) { u[row] = su * LOG2E; v[row] = sv * LOG2E; }
  }
}

// ---------------- prep: h_poT (bf16, [D][N]) ----------------
__global__ __launch_bounds__(256) void prep_T(
    const float* __restrict__ hpo, unsigned short* __restrict__ h_poT) {
  const int t = threadIdx.x;
  const int r0 = blockIdx.x * 64;
  unsigned short* dst = h_poT + (size_t)t * NN + r0;
#pragma unroll
  for (int c = 0; c < 16; ++c) {
    unsigned short x0 = f2bf(hpo[(size_t)(r0 + c * 4 + 0) * DD + t]);
    unsigned short x1 = f2bf(hpo[(size_t)(r0 + c * 4 + 1) * DD + t]);
    unsigned short x2 = f2bf(hpo[(size_t)(r0 + c * 4 + 2) * DD + t]);
    unsigned short x3 = f2bf(hpo[(size_t)(r0 + c * 4 + 3) * DD + t]);
    ((uint2*)dst)[c] = make_uint2((unsigned)x0 | ((unsigned)x1 << 16),
                                  (unsigned)x2 | ((unsigned)x3 << 16));
  }
}

// ---------------- pass 1: per-row coef (streaming, wave-independent) --------
__global__ __launch_bounds__(256) void stats_kernel(
    const float* __restrict__ adj, const float* __restrict__ u2,
    const float* __restrict__ v2, float* __restrict__ coef) {
  const int gw = blockIdx.x * 4 + (threadIdx.x >> 6);  // 0..4095
  const int lane = threadIdx.x & 63;
#pragma unroll
  for (int rr = 0; rr < 3; ++rr) {
    const int row = gw * 3 + rr;
    const float u_r = u2[row];
    const float* ap = adj + (size_t)row * NN;
    float qs = 0.f, as = 0.f;
    for (int c0 = lane * 8; c0 < NN; c0 += 512) {
      const float4 a0 = *(const float4*)(ap + c0);
      const float4 a1 = *(const float4*)(ap + c0 + 4);
      const float4 w0 = *(const float4*)(v2 + c0);
      const float4 w1 = *(const float4*)(v2 + c0 + 4);
      const float aa[8] = {a0.x, a0.y, a0.z, a0.w, a1.x, a1.y, a1.z, a1.w};
      const float ww[8] = {w0.x, w0.y, w0.z, w0.w, w1.x, w1.y, w1.z, w1.w};
#pragma unroll
      for (int e = 0; e < 8; ++e) {
        const float s = u_r + ww[e];
        const float x = fmaxf(s, 0.01f * s);
        const float q = exp2_hw(x - SHIFT2);
        qs += (aa[e] > 0.f) ? q : 0.f;
        as += aa[e];
      }
    }
#pragma unroll
    for (int m = 32; m; m >>= 1) {
      qs += __shfl_xor(qs, m, 64);
      as += __shfl_xor(as, m, 64);
    }
    if (lane == 0) coef[row] = qs > 0.f ? 0.5f * as / qs : 0.f;
  }
}

// ---------------- pass 2: fused5 GEMM with computed A ----------------
__global__ __launch_bounds__(256, 3) void fused5(
    const float* __restrict__ adj, const float* __restrict__ u2,
    const float* __restrict__ v2, const float* __restrict__ coef,
    const unsigned short* __restrict__ h_poT, float* __restrict__ out) {
  __shared__ float sh_adj[2][16 * KC];  // 16 KB: adj chunk, dbuf, swizzled
  __shared__ float sh_v[2][KC];         // 1 KB

  const int t = threadIdx.x;
  const int w = t >> 6, lane = t & 63;
  const int lrow = lane & 15, kgrp = lane >> 4;
  const int i0 = blockIdx.x * 16;
  const int row = i0 + lrow;

  const float u_r = u2[row];
  const float cf_r = coef[row];

  // global_load_lds: wave w, instr i covers LDS bytes [w*2048+i*1024, +1024)
  // (HW adds lane*16 to the uniform base). Pre-swizzled source so that the
  // read-side XOR sees logical [r][c] at byte r*512 + (c*4 ^ ((r&7)<<4)).
  size_t srcoff[2];
#pragma unroll
  for (int i = 0; i < 2; ++i) {
    const int L = w * 2048 + i * 1024 + lane * 16;
    const int r = L >> 9;
    const int c = ((L & 511) ^ ((r & 7) << 4)) >> 2;
    srcoff[i] = (size_t)(i0 + r) * NN + c;
  }

  // B fragment base pointers (bf16 h_poT, row-contiguous k)
  const unsigned short* bp0 = h_poT + (size_t)(w * 64 + 0 * 16 + lrow) * NN + kgrp * 8;
  const unsigned short* bp1 = h_poT + (size_t)(w * 64 + 1 * 16 + lrow) * NN + kgrp * 8;
  const unsigned short* bp2 = h_poT + (size_t)(w * 64 + 2 * 16 + lrow) * NN + kgrp * 8;
  const unsigned short* bp3 = h_poT + (size_t)(w * 64 + 3 * 16 + lrow) * NN + kgrp * 8;

  f32x4 acc[4] = {};
  const int xr = (lrow & 7) << 4;

  // prologue: stage chunk 0
  {
#pragma unroll
    for (int i = 0; i < 2; ++i)
      gl_lds16(adj + srcoff[i], &sh_adj[0][w * 512 + i * 256]);
    if (t < 32) *(float4*)&sh_v[0][t * 4] = *(const float4*)&v2[t * 4];
  }
  __syncthreads();

  for (int ci = 0; ci < NCH; ++ci) {
    const int buf = ci & 1;
    const int j = ci * KC;
    // prefetch next chunk (in flight across this chunk's compute)
    if (ci + 1 < NCH) {
      const int jn = j + KC;
#pragma unroll
      for (int i = 0; i < 2; ++i)
        gl_lds16(adj + srcoff[i] + jn, &sh_adj[buf ^ 1][w * 512 + i * 256]);
      if (t < 32) *(float4*)&sh_v[buf ^ 1][t * 4] = *(const float4*)&v2[jn + t * 4];
    }

    // B burst: 16 x dwordx4 into static regs (one vmcnt batch)
    uint4 b[4][4];
#pragma unroll
    for (int s = 0; s < 4; ++s) {
      b[s][0] = *(const uint4*)(bp0 + j + s * 32);
      b[s][1] = *(const uint4*)(bp1 + j + s * 32);
      b[s][2] = *(const uint4*)(bp2 + j + s * 32);
      b[s][3] = *(const uint4*)(bp3 + j + s * 32);
    }

    const char* sbase = (const char*)sh_adj + buf * (16 * KC * 4) + lrow * 512;
#pragma unroll
    for (int s = 0; s < 4; ++s) {
      const int c4 = s * 128 + kgrp * 32;  // byte offset of this lane's 8 floats
      const f32x4 A0 = *(const f32x4*)(sbase + (c4 ^ xr));
      const f32x4 A1 = *(const f32x4*)(sbase + ((c4 + 16) ^ xr));
      const f32x4 V0 = *(const f32x4*)&sh_v[buf][s * 32 + kgrp * 8];
      const f32x4 V1 = *(const f32x4*)&sh_v[buf][s * 32 + kgrp * 8 + 4];

      const float af[8] = {A0[0], A0[1], A0[2], A0[3], A1[0], A1[1], A1[2], A1[3]};
      const float vf[8] = {V0[0], V0[1], V0[2], V0[3], V1[0], V1[1], V1[2], V1[3]};
      float val[8];
#pragma unroll
      for (int e = 0; e < 8; ++e) {
        const float sx = u_r + vf[e];
        const float x = fmaxf(sx, 0.01f * sx);
        const float q = exp2_hw(x - SHIFT2);
        const float base = 0.5f * af[e];
        val[e] = (af[e] > 0.f) ? fmaf(cf_r, q, base) : base;
      }
      unsigned qp[4];
#pragma unroll
      for (int e = 0; e < 4; ++e) qp[e] = pack_bf2(val[2 * e], val[2 * e + 1]);
      const s16x8 qa = __builtin_bit_cast(s16x8, *(uint4*)qp);

      acc[0] = __builtin_amdgcn_mfma_f32_16x16x32_bf16(qa, __builtin_bit_cast(s16x8, b[s][0]), acc[0], 0, 0, 0);
      acc[1] = __builtin_amdgcn_mfma_f32_16x16x32_bf16(qa, __builtin_bit_cast(s16x8, b[s][1]), acc[1], 0, 0, 0);
      acc[2] = __builtin_amdgcn_mfma_f32_16x16x32_bf16(qa, __builtin_bit_cast(s16x8, b[s][2]), acc[2], 0, 0, 0);
      acc[3] = __builtin_amdgcn_mfma_f32_16x16x32_bf16(qa, __builtin_bit_cast(s16x8, b[s][3]), acc[3], 0, 0, 0);
    }
    __syncthreads();  // drains prefetch (had full chunk to land) + buffer swap
  }

  // epilogue: C/D layout col=lane&15, row=kgrp*4+g (proven r2)
#pragma unroll
  for (int dt = 0; dt < 4; ++dt) {
    const int col = w * 64 + dt * 16 + lrow;
#pragma unroll
    for (int g = 0; g < 4; ++g)
      out[(size_t)(i0 + kgrp * 4 + g) * DD + col] = acc[dt][g];
  }
}

// ---------------- fallback (small ws): round-2 proven kernel ----------------
__global__ __launch_bounds__(256) void fused_fb(
    const float* __restrict__ adj, const float* __restrict__ u,
    const float* __restrict__ v, const float* __restrict__ hpo,
    float* __restrict__ out) {
#define BMF 32
#define LDA 40
  __shared__ unsigned short qlds[BMF][LDA];
  __shared__ unsigned short alds[BMF][LDA];
  __shared__ unsigned short btf[DD][LDA];
  __shared__ float denom_s[BMF], deg_s[BMF], coef_s[BMF];

  const int t = threadIdx.x;
  const int wave = t >> 6, lane = t & 63;
  const int i0 = blockIdx.x * BMF;
  const int sr = t >> 3;
  const int sc = (t & 7) * 4;
  const float u_r = u[i0 + sr];
  const int d0 = wave * 64;
  const int lrow = lane & 15;
  const int kgrp = lane >> 4;

  f32x4 acc1[2][4] = {};
  f32x4 acc2[2][4] = {};
  float qsum = 0.f, asum = 0.f;

  const float* arow = adj + (size_t)(i0 + sr) * NN + sc;
  float4 a_cur = *(const float4*)(arow);

  constexpr int NSTEP = NN / 32;
  for (int jt = 0; jt < NSTEP; ++jt) {
    const int j = jt * 32;
    float4 a_nxt;
    const bool has_next = (jt + 1 < NSTEP);
    if (has_next) a_nxt = *(const float4*)(arow + j + 32);
    const float4 vv = *(const float4*)(v + j + sc);
    unsigned short qb[4], ab[4];
    {
      const float aa4[4] = {a_cur.x, a_cur.y, a_cur.z, a_cur.w};
      const float vvv[4] = {vv.x, vv.y, vv.z, vv.w};
#pragma unroll
      for (int k = 0; k < 4; ++k) {
        const float a = aa4[k];
        const float s = u_r + vvv[k];
        const float x = fmaxf(s, 0.01f * s);
        const float q = (a > 0.f) ? exp2_hw(x - SHIFT2) : 0.f;
        qsum += q;
        asum += a;
        qb[k] = f2bf(q);
        ab[k] = f2bf(a);
      }
    }
    *(uint2*)&qlds[sr][sc] = make_uint2((unsigned)qb[0] | ((unsigned)qb[1] << 16),
                                        (unsigned)qb[2] | ((unsigned)qb[3] << 16));
    *(uint2*)&alds[sr][sc] = make_uint2((unsigned)ab[0] | ((unsigned)ab[1] << 16),
                                        (unsigned)ab[2] | ((unsigned)ab[3] << 16));
    {
      const int br = t >> 3;
      const float* src = hpo + (size_t)(j + br) * DD;
#pragma unroll
      for (int cc = 0; cc < 8; ++cc) {
        const int c = (t & 7) * 4 + cc * 32;
        const float4 hv = *(const float4*)(src + c);
        btf[c + 0][br] = f2bf(hv.x);
        btf[c + 1][br] = f2bf(hv.y);
        btf[c + 2][br] = f2bf(hv.z);
        btf[c + 3][br] = f2bf(hv.w);
      }
    }
    __syncthreads();

    const s16x8 qa0 = *(const s16x8*)&qlds[lrow][kgrp * 8];
    const s16x8 qa1 = *(const s16x8*)&qlds[16 + lrow][kgrp * 8];
    const s16x8 ad0 = *(const s16x8*)&alds[lrow][kgrp * 8];
    const s16x8 ad1 = *(const s16x8*)&alds[16 + lrow][kgrp * 8];
#pragma unroll
    for (int dt = 0; dt < 4; ++dt) {
      const s16x8 b = *(const s16x8*)&btf[d0 + dt * 16 + lrow][kgrp * 8];
      acc1[0][dt] = __builtin_amdgcn_mfma_f32_16x16x32_bf16(qa0, b, acc1[0][dt], 0, 0, 0);
      acc1[1][dt] = __builtin_amdgcn_mfma_f32_16x16x32_bf16(qa1, b, acc1[1][dt], 0, 0, 0);
      acc2[0][dt] = __builtin_amdgcn_mfma_f32_16x16x32_bf16(ad0, b, acc2[0][dt], 0, 0, 0);
      acc2[1][dt] = __builtin_amdgcn_mfma_f32_16x16x32_bf16(ad1, b, acc2[1][dt], 0, 0, 0);
    }
    __syncthreads();
    if (has_next) a_cur = a_nxt;
  }
#pragma unroll
  for (int m = 1; m <= 4; m <<= 1) {
    qsum += __shfl_xor(qsum, m, 64);
    asum += __shfl_xor(asum, m, 64);
  }
  if ((t & 7) == 0) { denom_s[sr] = qsum; deg_s[sr] = asum; }
  __syncthreads();
  if (t < BMF) {
    const float dn = denom_s[t];
    coef_s[t] = dn > 0.f ? 0.5f * deg_s[t] / dn : 0.f;
  }
  __syncthreads();
#pragma unroll
  for (int f = 0; f < 2; ++f) {
#pragma unroll
    for (int dt = 0; dt < 4; ++dt) {
      const int col = d0 + dt * 16 + lrow;
#pragma unroll
      for (int g = 0; g < 4; ++g) {
        const int r = f * 16 + kgrp * 4 + g;
        out[(size_t)(i0 + r) * DD + col] =
            coef_s[r] * acc1[f][dt][g] + 0.5f * acc2[f][dt][g];
      }
    }
  }
}

extern "C" void kernel_launch(void* const* d_in, const int* in_sizes, int n_in,
                              void* d_out, int out_size, void* d_ws, size_t ws_size,
                              hipStream_t stream) {
  const float* h_eu = (const float*)d_in[0];
  const float* h_po = (const float*)d_in[1];
  const float* h_lo = (const float*)d_in[2];
  const float* adj  = (const float*)d_in[3];
  const float* a1   = (const float*)d_in[4];
  const float* a2   = (const float*)d_in[5];
  const float* a3   = (const float*)d_in[6];
  float* out = (float*)d_out;

  // ws layout: u[N] | v[N] | coef[N] | h_poT[D*N] bf16  = 6,438,912 B
  const size_t need_full = (size_t)3 * NN * 4 + (size_t)NN * DD * 2;
  float* u = (float*)d_ws;
  float* v = u + NN;
  float* coef = v + NN;
  unsigned short* h_poT = (unsigned short*)(coef + NN);
  const bool big_ws = ws_size >= need_full;

  prep_uv<<<NN / 64, 256, 0, stream>>>(h_eu, h_po, h_lo, a1, a2, a3, u, v);
  if (big_ws) {
    prep_T<<<NN / 64, 256, 0, stream>>>(h_po, h_poT);
    stats_kernel<<<1024, 256, 0, stream>>>(adj, u, v, coef);
    fused5<<<NN / 16, 256, 0, stream>>>(adj, u, v, coef, h_poT, out);
  } else {
    fused_fb<<<NN / 32, 256, 0, stream>>>(adj, u, v, h_po, out);
  }
}

// Round 7
// 331.501 us; speedup vs baseline: 3.4665x; 2.1932x over previous
//
#include <hip/hip_runtime.h>
#include <hip/hip_bf16.h>

// N=12288, D=256. Single pass:
//   e=lrelu(u_i+v_j); q=exp2(e*log2e-SHIFT2) masked adj>0 (const shift, scale-free)
//   out_i = coef_i*(q_i@h_po) + 0.5*(adj_i@h_po),  coef_i=0.5*deg_i/denom_i
// fused7: BM=48, grid 256 (exactly 1 block/CU), 768 threads = 12 waves =
// (3 row-groups x 2 D-halves x 2 k-slices). Both adj and B tiles staged by
// global_load_lds w16 (dbuf, BK=64, one barrier/step), XOR-swizzled via
// pre-swizzled SOURCE addresses (linear LDS dest), fragments via ds_read_b128.

#define NN 12288
#define DD 256
#define BM 48
#define BK 64
#define NSTEPS (NN / BK)   // 192
#define LOG2E 1.44269504f
#define SHIFT2 36.067376f  // 25*log2e

typedef __attribute__((ext_vector_type(8))) short s16x8;
typedef __attribute__((ext_vector_type(4))) float f32x4;

__device__ __forceinline__ unsigned short f2bf(float f) {
  unsigned u = __builtin_bit_cast(unsigned, f);
  u += 0x7FFFu + ((u >> 16) & 1u);
  return (unsigned short)(u >> 16);
}
__device__ __forceinline__ unsigned pack_bf2(float a, float b) {
  unsigned short lo = __builtin_bit_cast(unsigned short, __float2bfloat16(a));
  unsigned short hi = __builtin_bit_cast(unsigned short, __float2bfloat16(b));
  return (unsigned)lo | ((unsigned)hi << 16);
}
__device__ __forceinline__ float exp2_hw(float x) {
  float r;
  asm("v_exp_f32 %0, %1" : "=v"(r) : "v"(x));
  return r;
}
__device__ __forceinline__ void gl_lds16(const void* g, void* l) {
  __builtin_amdgcn_global_load_lds(
      (const __attribute__((address_space(1))) void*)g,
      (__attribute__((address_space(3))) void*)l, 16, 0, 0);
}

// ---------------- prep: u2, v2 (pre-scaled by log2e) ----------------
__global__ __launch_bounds__(256) void prep_uv(
    const float* __restrict__ h_eu, const float* __restrict__ h_po,
    const float* __restrict__ h_lo, const float* __restrict__ a1,
    const float* __restrict__ a2, const float* __restrict__ a3,
    float* __restrict__ u, float* __restrict__ v) {
  const int t = threadIdx.x;
  const int wave = t >> 6, lane = t & 63;
  const int r0 = blockIdx.x * 64;
  for (int rr = 0; rr < 16; ++rr) {
    const int row = r0 + wave * 16 + rr;
    const float* pe = h_eu + (size_t)row * DD;
    const float* pl = h_lo + (size_t)row * DD;
    const float* pp = h_po + (size_t)row * DD;
    float su = 0.f, sv = 0.f;
#pragma unroll
    for (int c = 0; c < 4; ++c) {
      const int d = lane + c * 64;
      su = fmaf(pe[d], a1[d], su);
      su = fmaf(pl[d], a3[d], su);
      sv = fmaf(pp[d], a2[d], sv);
    }
#pragma unroll
    for (int m = 32; m; m >>= 1) {
      su += __shfl_xor(su, m, 64);
      sv += __shfl_xor(sv, m, 64);
    }
    if (lane == 0) { u[row] = su * LOG2E; v[row] = sv * LOG2E; }
  }
}

// ---------------- prep: h_poT (bf16, [D][N]) ----------------
__global__ __launch_bounds__(256) void prep_T(
    const float* __restrict__ hpo, unsigned short* __restrict__ h_poT) {
  const int t = threadIdx.x;
  const int r0 = blockIdx.x * 64;
  unsigned short* dst = h_poT + (size_t)t * NN + r0;
#pragma unroll
  for (int c = 0; c < 16; ++c) {
    unsigned short x0 = f2bf(hpo[(size_t)(r0 + c * 4 + 0) * DD + t]);
    unsigned short x1 = f2bf(hpo[(size_t)(r0 + c * 4 + 1) * DD + t]);
    unsigned short x2 = f2bf(hpo[(size_t)(r0 + c * 4 + 2) * DD + t]);
    unsigned short x3 = f2bf(hpo[(size_t)(r0 + c * 4 + 3) * DD + t]);
    ((uint2*)dst)[c] = make_uint2((unsigned)x0 | ((unsigned)x1 << 16),
                                  (unsigned)x2 | ((unsigned)x3 << 16));
  }
}

// ---------------- fused7 ----------------
__global__ __launch_bounds__(768) void fused7(
    const float* __restrict__ adj, const float* __restrict__ u2,
    const float* __restrict__ v2, const unsigned short* __restrict__ h_poT,
    float* __restrict__ out) {
  __shared__ __align__(16) char sAdj[2][BM * 256];   // 24 KB: [r][swz 256 B]
  __shared__ __align__(16) char sB[2][DD * 128];     // 64 KB: [d][swz 128 B]
  __shared__ float sq[2][3][16], sa[2][3][16];

  const int t = threadIdx.x;
  const int w = t >> 6, lane = t & 63;
  const int rg = w >> 2;           // 0..2  row-group (16 rows)
  const int dh = (w >> 1) & 1;     // 0..1  D-half (128 cols)
  const int kh = w & 1;            // 0..1  k-slice (32 of the 64-k step)
  const int lrow = lane & 15, kgrp = lane >> 4;
  const int i0 = blockIdx.x * BM;
  const int row = i0 + rg * 16 + lrow;
  const float u_r = u2[row];
  const int xr = (lrow & 7) << 4;

  // staging: 44 x 1KB gl_lds instrs (12 adj + 32 B), wave w takes idx w,w+12,...
  // adj tile: logical (r,k) at byte r*256 + ((k*4) ^ ((r&7)<<4))
  // B   tile: logical (d,k) at byte d*128 + ((k*2) ^ ((d&7)<<4))
  // dest is linear (base + lane*16) so SOURCE carries the inverse swizzle.
  auto STAGE = [&](int buf, int j) {
    for (int idx = w; idx < 44; idx += 12) {
      if (idx < 12) {
        const int r = idx * 4 + (lane >> 4);
        const int k4 = ((lane & 15) ^ ((idx & 1) * 4 + (lane >> 4))) << 2;
        gl_lds16(adj + (size_t)(i0 + r) * NN + j + k4, &sAdj[buf][idx * 1024]);
      } else {
        const int ib = idx - 12;
        const int d = ib * 8 + (lane >> 3);
        const int ko = ((lane & 7) ^ (lane >> 3)) * 8;
        gl_lds16(h_poT + (size_t)d * NN + j + ko, &sB[buf][ib * 1024]);
      }
    }
  };

  f32x4 acc1[8] = {};  // q   @ B  (8 dt of this D-half)
  f32x4 acc2[8] = {};  // adj @ B
  float qsum = 0.f, asum = 0.f;

  const float* vbase = v2 + kh * 32 + kgrp * 8;
  STAGE(0, 0);
  float4 V0 = *(const float4*)(vbase);
  float4 V1 = *(const float4*)(vbase + 4);
  __syncthreads();

  for (int s = 0; s < NSTEPS; ++s) {
    const int buf = s & 1;
    const bool more = (s + 1 < NSTEPS);
    if (more) STAGE(buf ^ 1, (s + 1) * BK);
    float4 Vn0, Vn1;
    if (more) {
      Vn0 = *(const float4*)(vbase + (s + 1) * BK);
      Vn1 = *(const float4*)(vbase + (s + 1) * BK + 4);
    }

    // adj fragment: row rg*16+lrow, k = kh*32 + kgrp*8 .. +8
    const char* abase = &sAdj[buf][(rg * 16 + lrow) * 256];
    const int kb0 = kh * 128 + kgrp * 32;
    const f32x4 A0 = *(const f32x4*)(abase + (kb0 ^ xr));
    const f32x4 A1 = *(const f32x4*)(abase + ((kb0 + 16) ^ xr));

    const float af[8] = {A0[0], A0[1], A0[2], A0[3], A1[0], A1[1], A1[2], A1[3]};
    const float vf[8] = {V0.x, V0.y, V0.z, V0.w, V1.x, V1.y, V1.z, V1.w};
    float qv[8];
#pragma unroll
    for (int e = 0; e < 8; ++e) {
      const float sx = u_r + vf[e];
      const float x = fmaxf(sx, 0.01f * sx);
      float q = exp2_hw(x - SHIFT2);
      q = (af[e] > 0.f) ? q : 0.f;
      qsum += q;
      asum += af[e];
      qv[e] = q;
    }
    unsigned qp[4], ap[4];
#pragma unroll
    for (int e = 0; e < 4; ++e) {
      qp[e] = pack_bf2(qv[2 * e], qv[2 * e + 1]);
      ap[e] = pack_bf2(af[2 * e], af[2 * e + 1]);
    }
    const s16x8 qa = __builtin_bit_cast(s16x8, *(uint4*)qp);
    const s16x8 aa = __builtin_bit_cast(s16x8, *(uint4*)ap);

    // B fragments + MFMA (8 dt of this D-half, this k-slice)
    const char* bb0 = &sB[buf][0];
    const int bk0 = kh * 64 + kgrp * 16;
#pragma unroll
    for (int dt = 0; dt < 8; ++dt) {
      const int d = dh * 128 + dt * 16 + lrow;
      const s16x8 bb = *(const s16x8*)(bb0 + d * 128 + (bk0 ^ xr));
      acc1[dt] = __builtin_amdgcn_mfma_f32_16x16x32_bf16(qa, bb, acc1[dt], 0, 0, 0);
      acc2[dt] = __builtin_amdgcn_mfma_f32_16x16x32_bf16(aa, bb, acc2[dt], 0, 0, 0);
    }
    __syncthreads();  // drains this step's prefetch; swaps buffers
    if (more) { V0 = Vn0; V1 = Vn1; }
  }

  // ---- stats: per-row sums (this wave's k-slice) -> LDS ----
  qsum += __shfl_xor(qsum, 16, 64); qsum += __shfl_xor(qsum, 32, 64);
  asum += __shfl_xor(asum, 16, 64); asum += __shfl_xor(asum, 32, 64);
  if (dh == 0 && lane < 16) { sq[kh][rg][lane] = qsum; sa[kh][rg][lane] = asum; }
  __syncthreads();

  // ---- fold coef, reduce over kh via LDS (reuse sB: 48 KB), write out ----
  f32x4 fin[8];
#pragma unroll
  for (int dt = 0; dt < 8; ++dt) {
#pragma unroll
    for (int g = 0; g < 4; ++g) {
      const int rr = kgrp * 4 + g;
      const float qq = sq[0][rg][rr] + sq[1][rg][rr];
      const float aa2 = sa[0][rg][rr] + sa[1][rg][rr];
      const float cfr = qq > 0.f ? 0.5f * aa2 / qq : 0.f;
      fin[dt][g] = cfr * acc1[dt][g] + 0.5f * acc2[dt][g];
    }
  }
  float* red = (float*)sB;  // [(rg*2+dh)*8+dt][lane][4] = 49,152 B
  const int rbase = ((rg * 2 + dh) * 8 * 64 + lane) * 4;
  if (kh == 1) {
#pragma unroll
    for (int dt = 0; dt < 8; ++dt) *(f32x4*)&red[rbase + dt * 256] = fin[dt];
  }
  __syncthreads();
  if (kh == 0) {
#pragma unroll
    for (int dt = 0; dt < 8; ++dt) {
      const f32x4 o = *(const f32x4*)&red[rbase + dt * 256];
      const int col = dh * 128 + dt * 16 + lrow;
#pragma unroll
      for (int g = 0; g < 4; ++g)
        out[(size_t)(i0 + rg * 16 + kgrp * 4 + g) * DD + col] = fin[dt][g] + o[g];
    }
  }
}

// ---------------- fallback (small ws): round-2 proven kernel ----------------
__global__ __launch_bounds__(256) void fused_fb(
    const float* __restrict__ adj, const float* __restrict__ u,
    const float* __restrict__ v, const float* __restrict__ hpo,
    float* __restrict__ out) {
#define BMF 32
#define LDA 40
  __shared__ unsigned short qlds[BMF][LDA];
  __shared__ unsigned short alds[BMF][LDA];
  __shared__ unsigned short btf[DD][LDA];
  __shared__ float denom_s[BMF], deg_s[BMF], coef_s[BMF];

  const int t = threadIdx.x;
  const int wave = t >> 6, lane = t & 63;
  const int i0 = blockIdx.x * BMF;
  const int sr = t >> 3;
  const int sc = (t & 7) * 4;
  const float u_r = u[i0 + sr];
  const int d0 = wave * 64;
  const int lrow = lane & 15;
  const int kgrp = lane >> 4;

  f32x4 acc1[2][4] = {};
  f32x4 acc2[2][4] = {};
  float qsum = 0.f, asum = 0.f;

  const float* arow = adj + (size_t)(i0 + sr) * NN + sc;
  float4 a_cur = *(const float4*)(arow);

  constexpr int NSTEP = NN / 32;
  for (int jt = 0; jt < NSTEP; ++jt) {
    const int j = jt * 32;
    float4 a_nxt;
    const bool has_next = (jt + 1 < NSTEP);
    if (has_next) a_nxt = *(const float4*)(arow + j + 32);
    const float4 vv = *(const float4*)(v + j + sc);
    unsigned short qb[4], ab[4];
    {
      const float aa4[4] = {a_cur.x, a_cur.y, a_cur.z, a_cur.w};
      const float vvv[4] = {vv.x, vv.y, vv.z, vv.w};
#pragma unroll
      for (int k = 0; k < 4; ++k) {
        const float a = aa4[k];
        const float s = u_r + vvv[k];
        const float x = fmaxf(s, 0.01f * s);
        const float q = (a > 0.f) ? exp2_hw(x - SHIFT2) : 0.f;
        qsum += q;
        asum += a;
        qb[k] = f2bf(q);
        ab[k] = f2bf(a);
      }
    }
    *(uint2*)&qlds[sr][sc] = make_uint2((unsigned)qb[0] | ((unsigned)qb[1] << 16),
                                        (unsigned)qb[2] | ((unsigned)qb[3] << 16));
    *(uint2*)&alds[sr][sc] = make_uint2((unsigned)ab[0] | ((unsigned)ab[1] << 16),
                                        (unsigned)ab[2] | ((unsigned)ab[3] << 16));
    {
      const int br = t >> 3;
      const float* src = hpo + (size_t)(j + br) * DD;
#pragma unroll
      for (int cc = 0; cc < 8; ++cc) {
        const int c = (t & 7) * 4 + cc * 32;
        const float4 hv = *(const float4*)(src + c);
        btf[c + 0][br] = f2bf(hv.x);
        btf[c + 1][br] = f2bf(hv.y);
        btf[c + 2][br] = f2bf(hv.z);
        btf[c + 3][br] = f2bf(hv.w);
      }
    }
    __syncthreads();

    const s16x8 qa0 = *(const s16x8*)&qlds[lrow][kgrp * 8];
    const s16x8 qa1 = *(const s16x8*)&qlds[16 + lrow][kgrp * 8];
    const s16x8 ad0 = *(const s16x8*)&alds[lrow][kgrp * 8];
    const s16x8 ad1 = *(const s16x8*)&alds[16 + lrow][kgrp * 8];
#pragma unroll
    for (int dt = 0; dt < 4; ++dt) {
      const s16x8 b = *(const s16x8*)&btf[d0 + dt * 16 + lrow][kgrp * 8];
      acc1[0][dt] = __builtin_amdgcn_mfma_f32_16x16x32_bf16(qa0, b, acc1[0][dt], 0, 0, 0);
      acc1[1][dt] = __builtin_amdgcn_mfma_f32_16x16x32_bf16(qa1, b, acc1[1][dt], 0, 0, 0);
      acc2[0][dt] = __builtin_amdgcn_mfma_f32_16x16x32_bf16(ad0, b, acc2[0][dt], 0, 0, 0);
      acc2[1][dt] = __builtin_amdgcn_mfma_f32_16x16x32_bf16(ad1, b, acc2[1][dt], 0, 0, 0);
    }
    __syncthreads();
    if (has_next) a_cur = a_nxt;
  }
#pragma unroll
  for (int m = 1; m <= 4; m <<= 1) {
    qsum += __shfl_xor(qsum, m, 64);
    asum += __shfl_xor(asum, m, 64);
  }
  if ((t & 7) == 0) { denom_s[sr] = qsum; deg_s[sr] = asum; }
  __syncthreads();
  if (t < BMF) {
    const float dn = denom_s[t];
    coef_s[t] = dn > 0.f ? 0.5f * deg_s[t] / dn : 0.f;
  }
  __syncthreads();
#pragma unroll
  for (int f = 0; f < 2; ++f) {
#pragma unroll
    for (int dt = 0; dt < 4; ++dt) {
      const int col = d0 + dt * 16 + lrow;
#pragma unroll
      for (int g = 0; g < 4; ++g) {
        const int r = f * 16 + kgrp * 4 + g;
        out[(size_t)(i0 + r) * DD + col] =
            coef_s[r] * acc1[f][dt][g] + 0.5f * acc2[f][dt][g];
      }
    }
  }
}

extern "C" void kernel_launch(void* const* d_in, const int* in_sizes, int n_in,
                              void* d_out, int out_size, void* d_ws, size_t ws_size,
                              hipStream_t stream) {
  const float* h_eu = (const float*)d_in[0];
  const float* h_po = (const float*)d_in[1];
  const float* h_lo = (const float*)d_in[2];
  const float* adj  = (const float*)d_in[3];
  const float* a1   = (const float*)d_in[4];
  const float* a2   = (const float*)d_in[5];
  const float* a3   = (const float*)d_in[6];
  float* out = (float*)d_out;

  // ws layout: u[N] | v[N] | h_poT[D*N] bf16 = 6,389,760 B
  const size_t need_full = (size_t)2 * NN * 4 + (size_t)NN * DD * 2;
  float* u = (float*)d_ws;
  float* v = u + NN;
  unsigned short* h_poT = (unsigned short*)(v + NN);
  const bool big_ws = ws_size >= need_full;

  prep_uv<<<NN / 64, 256, 0, stream>>>(h_eu, h_po, h_lo, a1, a2, a3, u, v);
  if (big_ws) {
    prep_T<<<NN / 64, 256, 0, stream>>>(h_po, h_poT);
    fused7<<<NN / BM, 768, 0, stream>>>(adj, u, v, h_poT, out);
  } else {
    fused_fb<<<NN / 32, 256, 0, stream>>>(adj, u, v, h_po, out);
  }
}